// Round 10
// baseline (1358.332 us; speedup 1.0000x reference)
//
#include <hip/hip_runtime.h>

#define NE     800000
#define NWT    50000          // 16-edge wave-tiles
#define GRID   1024           // 256-thr blocks, 4 blocks/CU target
#define HP     200            // ushort pitch of H rows (400 B)

typedef __attribute__((ext_vector_type(8))) short short8;   // 8 x bf16
typedef __attribute__((ext_vector_type(4))) float f32x4;

// f32 -> bf16 bits, round-to-nearest-even
__device__ __forceinline__ ushort f2b(float f) {
    unsigned u = __float_as_uint(f);
    return (ushort)((u + 0x7FFFu + ((u >> 16) & 1u)) >> 16);
}

// Pack W1 (192x192) and W2 (192x64) f32 -> bf16 MFMA B-fragments in d_ws.
// Entry e = t*6+k (e<72: W1; e>=72: W2). Lane l supplies
// B[k*32 + (l>>4)*8 + j][t*16 + (l&15)], j=0..7  (16 B per lane).
// (verified across R2/R4-R9, absmax 0.031)
__global__ void pack_w(const float* __restrict__ W1, const float* __restrict__ W2,
                       uint4* __restrict__ wsW)
{
    int i = blockIdx.x * 256 + threadIdx.x;     // 0..6143
    int lane = i & 63, e = i >> 6;
    const float* W; int N, t, k;
    if (e < 72) { W = W1; N = 192; t = e / 6; k = e - t * 6; }
    else        { int e2 = e - 72; W = W2; N = 64; t = e2 / 6; k = e2 - t * 6; }
    const float* p = W + (size_t)(k * 32 + (lane >> 4) * 8) * N + t * 16 + (lane & 15);
    ushort u[8];
    #pragma unroll
    for (int j = 0; j < 8; ++j) u[j] = f2b(p[(size_t)j * N]);
    uint4 d;
    d.x = u[0] | ((unsigned)u[1] << 16);
    d.y = u[2] | ((unsigned)u[3] << 16);
    d.z = u[4] | ((unsigned)u[5] << 16);
    d.w = u[6] | ((unsigned)u[7] << 16);
    wsW[i] = d;
}

// One wave = one 16-edge tile, fully independent (no in-loop barriers).
// 256-thr blocks, LDS only per-wave H (6.4 KB) + const table (2.5 KB)
// -> ~28 KB/block -> 4 blocks/CU, 4 waves/SIMD. W streamed from L2.
// Gather in two register halves (peak live ~108 VGPR, no spill).
__global__ __launch_bounds__(256, 4)
void edge_kernel(const float* __restrict__ nf, const float* __restrict__ ef,
                 const int* __restrict__ ei,
                 const float* __restrict__ b1g, const float* __restrict__ gg,
                 const float* __restrict__ btg, const float* __restrict__ b2g,
                 const uint4* __restrict__ wsW, float* __restrict__ out)
{
    __shared__ __align__(16) ushort Hs[4][16 * HP];  // 25600 B
    __shared__ float cs[640];                        // b1 | gamma | beta | b2

    const int tid  = threadIdx.x, w = tid >> 6, lane = tid & 63;
    const int lrow = lane & 15, lg = lane >> 4;
    ushort* H = Hs[w];

    for (int i = tid; i < 640; i += 256) {
        float v;
        if (i < 192)      v = b1g[i];
        else if (i < 384) v = gg[i - 192];
        else if (i < 576) v = btg[i - 384];
        else              v = b2g[i - 576];
        cs[i] = v;
    }
    __syncthreads();                 // cs visible; only barrier in the kernel

    for (int wt = blockIdx.x * 4 + w; wt < NWT; wt += GRID * 4) {
        const int e0 = wt * 16;

        // ---- indices: lanes 0..15 row idx, 16..31 col idx ----
        int iv = 0;
        if (lane < 32) iv = ei[(lane >> 4) * NE + e0 + lrow];
        int ir = __shfl(iv, lrow, 64);
        int ic = __shfl(iv, 16 + lrow, 64);
        const float* pr = nf + (size_t)ir * 64 + lg * 8;
        const float* pc = nf + (size_t)ic * 64 + lg * 8;
        const float* pe = ef + (size_t)(e0 + lrow) * 64 + lg * 8;

        // ---- gather half 1 (cols 0..95) -> xf[0..2] ----
        short8 xf[6];
        {
            float4 xv[6];
            xv[0] = *(const float4*)(pr);      xv[1] = *(const float4*)(pr + 4);
            xv[2] = *(const float4*)(pr + 32); xv[3] = *(const float4*)(pr + 36);
            xv[4] = *(const float4*)(pc);      xv[5] = *(const float4*)(pc + 4);
            #pragma unroll
            for (int ks = 0; ks < 3; ++ks) {
                float4 a = xv[2 * ks], b = xv[2 * ks + 1];
                xf[ks][0] = (short)f2b(a.x); xf[ks][1] = (short)f2b(a.y);
                xf[ks][2] = (short)f2b(a.z); xf[ks][3] = (short)f2b(a.w);
                xf[ks][4] = (short)f2b(b.x); xf[ks][5] = (short)f2b(b.y);
                xf[ks][6] = (short)f2b(b.z); xf[ks][7] = (short)f2b(b.w);
            }
        }
        // ---- gather half 2 (cols 96..191) -> xf[3..5] ----
        {
            float4 xv[6];
            xv[0] = *(const float4*)(pc + 32); xv[1] = *(const float4*)(pc + 36);
            xv[2] = *(const float4*)(pe);      xv[3] = *(const float4*)(pe + 4);
            xv[4] = *(const float4*)(pe + 32); xv[5] = *(const float4*)(pe + 36);
            #pragma unroll
            for (int ks = 0; ks < 3; ++ks) {
                float4 a = xv[2 * ks], b = xv[2 * ks + 1];
                xf[3 + ks][0] = (short)f2b(a.x); xf[3 + ks][1] = (short)f2b(a.y);
                xf[3 + ks][2] = (short)f2b(a.z); xf[3 + ks][3] = (short)f2b(a.w);
                xf[3 + ks][4] = (short)f2b(b.x); xf[3 + ks][5] = (short)f2b(b.y);
                xf[3 + ks][6] = (short)f2b(b.z); xf[3 + ks][7] = (short)f2b(b.w);
            }
        }

        // ---- GEMM1: 16x192 = X @ W1, A regs, B streamed from L2 ----
        f32x4 acc1[12];
        #pragma unroll
        for (int t = 0; t < 12; ++t) acc1[t] = (f32x4){0.f, 0.f, 0.f, 0.f};
        #pragma unroll
        for (int ks = 0; ks < 6; ++ks) {
            #pragma unroll
            for (int t = 0; t < 12; ++t) {
                short8 bf = *(const short8*)(wsW + (size_t)(t * 6 + ks) * 64 + lane);
                acc1[t] = __builtin_amdgcn_mfma_f32_16x16x32_bf16(xf[ks], bf, acc1[t], 0, 0, 0);
            }
        }

        // ---- +b1, LayerNorm (16-lane shfl reduce), relu, H -> wave LDS ----
        // D layout: row = lg*4+rr, col = t*16+lrow
        #pragma unroll
        for (int rr = 0; rr < 4; ++rr) {
            float s = 0.f, q = 0.f;
            #pragma unroll
            for (int t = 0; t < 12; ++t) {
                float v = acc1[t][rr] + cs[t * 16 + lrow];
                acc1[t][rr] = v;
                s += v; q += v * v;
            }
            #pragma unroll
            for (int msk = 1; msk < 16; msk <<= 1) {
                s += __shfl_xor(s, msk, 64);
                q += __shfl_xor(q, msk, 64);
            }
            float mean = s * (1.f / 192.f);
            float var  = q * (1.f / 192.f) - mean * mean;
            float rsv  = rsqrtf(var + 1e-5f);
            #pragma unroll
            for (int t = 0; t < 12; ++t) {
                float v = (acc1[t][rr] - mean) * rsv * cs[192 + t * 16 + lrow]
                          + cs[384 + t * 16 + lrow];
                H[(lg * 4 + rr) * HP + t * 16 + lrow] = f2b(fmaxf(v, 0.f));
            }
        }

        // ---- GEMM2: 16x64 = H @ W2 (in-wave LDS dep, no barrier) ----
        f32x4 acc2[4];
        #pragma unroll
        for (int t = 0; t < 4; ++t) acc2[t] = (f32x4){0.f, 0.f, 0.f, 0.f};
        #pragma unroll
        for (int ks = 0; ks < 6; ++ks) {
            short8 hf = *(const short8*)&H[lrow * HP + ks * 32 + lg * 8];
            #pragma unroll
            for (int t = 0; t < 4; ++t) {
                short8 bf = *(const short8*)(wsW + (size_t)(72 + t * 6 + ks) * 64 + lane);
                acc2[t] = __builtin_amdgcn_mfma_f32_16x16x32_bf16(hf, bf, acc2[t], 0, 0, 0);
            }
        }

        // ---- epilogue: + b2 + f32 edge residual (L2-hot), store ----
        #pragma unroll
        for (int t = 0; t < 4; ++t) {
            float b2v = cs[576 + t * 16 + lrow];
            #pragma unroll
            for (int rr = 0; rr < 4; ++rr) {
                int row = lg * 4 + rr;
                size_t o = (size_t)(e0 + row) * 64 + t * 16 + lrow;
                out[o] = acc2[t][rr] + b2v + ef[o];
            }
        }
    }
}

extern "C" void kernel_launch(void* const* d_in, const int* in_sizes, int n_in,
                              void* d_out, int out_size, void* d_ws, size_t ws_size,
                              hipStream_t stream) {
    const float* nf    = (const float*)d_in[0];
    const float* ef    = (const float*)d_in[1];
    const int*   ei    = (const int*)d_in[2];
    const float* W1    = (const float*)d_in[3];
    const float* b1    = (const float*)d_in[4];
    const float* gamma = (const float*)d_in[5];
    const float* beta  = (const float*)d_in[6];
    const float* W2    = (const float*)d_in[7];
    const float* b2    = (const float*)d_in[8];
    float* out = (float*)d_out;
    uint4* wsW = (uint4*)d_ws;   // 98304 B used

    hipLaunchKernelGGL(pack_w, dim3(24), dim3(256), 0, stream, W1, W2, wsW);
    hipLaunchKernelGGL(edge_kernel, dim3(GRID), dim3(256), 0, stream,
                       nf, ef, ei, b1, gamma, beta, b2, (const uint4*)wsW, out);
}